// Round 10
// baseline (527.147 us; speedup 1.0000x reference)
//
#include <hip/hip_runtime.h>

#define N_NODES 50000
#define N_EDGES 800000
#define F_IN    512
#define F_HID   256
#define F_OUT   60
#define SCAN_BLOCKS ((N_NODES + 255) / 256)   // 196

typedef __bf16    bf16x8 __attribute__((ext_vector_type(8)));
typedef __bf16    bf16x4 __attribute__((ext_vector_type(4)));
typedef float     f32x4  __attribute__((ext_vector_type(4)));
typedef _Float16  f16x4  __attribute__((ext_vector_type(4)));
typedef _Float16  f16x2  __attribute__((ext_vector_type(2)));

// Swizzled LDS index (bf16 units) for [row][32] tiles (64 B rows).
// slot = 16B group (8 bf16). XOR with (row>>1)&3: conflict-free ds_read_b128 /
// ds_write_b128 on both staging and fragment-read sides (bijective per row).
__device__ __forceinline__ int SWZ(int row, int slot) {
    return row * 32 + (((slot) ^ ((row >> 1) & 3)) << 3);
}

// ---------------- degree / CSR build ----------------
__global__ void k_cnt_zero(int* __restrict__ cnt) {
    int i = blockIdx.x * blockDim.x + threadIdx.x;
    if (i < N_NODES) cnt[i] = 0;
}
__global__ void k_deg_count(const int* __restrict__ dst, int* __restrict__ cnt) {
    int i = blockIdx.x * blockDim.x + threadIdx.x;
    if (i < N_EDGES) atomicAdd(&cnt[dst[i]], 1);
}
__global__ void k_dis(const int* __restrict__ cnt, float* __restrict__ dis) {
    int i = blockIdx.x * blockDim.x + threadIdx.x;
    if (i < N_NODES) dis[i] = rsqrtf((float)(cnt[i] + 1));   // +1 self loop
}
__global__ void k_scan1(const int* __restrict__ cnt, int* __restrict__ scanned,
                        int* __restrict__ blocksum) {
    __shared__ int tmp[256];
    int i = blockIdx.x * 256 + threadIdx.x;
    int v = (i < N_NODES) ? cnt[i] : 0;
    tmp[threadIdx.x] = v;
    __syncthreads();
    for (int off = 1; off < 256; off <<= 1) {
        int t = (threadIdx.x >= off) ? tmp[threadIdx.x - off] : 0;
        __syncthreads();
        tmp[threadIdx.x] += t;
        __syncthreads();
    }
    if (i < N_NODES) scanned[i] = tmp[threadIdx.x] - v;
    if (threadIdx.x == 255) blocksum[blockIdx.x] = tmp[255];
}
__global__ void k_scan2(const int* __restrict__ blocksum, int* __restrict__ blockoff) {
    __shared__ int tmp[256];
    int v = (threadIdx.x < SCAN_BLOCKS) ? blocksum[threadIdx.x] : 0;
    tmp[threadIdx.x] = v;
    __syncthreads();
    for (int off = 1; off < 256; off <<= 1) {
        int t = (threadIdx.x >= off) ? tmp[threadIdx.x - off] : 0;
        __syncthreads();
        tmp[threadIdx.x] += t;
        __syncthreads();
    }
    if (threadIdx.x < SCAN_BLOCKS) blockoff[threadIdx.x] = tmp[threadIdx.x] - v;
}
__global__ void k_scan3(const int* __restrict__ scanned, const int* __restrict__ blockoff,
                        int* __restrict__ row_ptr, int* __restrict__ cursor) {
    int i = blockIdx.x * 256 + threadIdx.x;
    if (i < N_NODES) {
        int rp = scanned[i] + blockoff[blockIdx.x];
        row_ptr[i] = rp;
        cursor[i] = rp;
    }
    if (i == 0) row_ptr[N_NODES] = N_EDGES;
}
__global__ void k_fill(const int* __restrict__ src, const int* __restrict__ dst,
                       int* __restrict__ cursor, int* __restrict__ esrc) {
    int e = blockIdx.x * blockDim.x + threadIdx.x;
    if (e < N_EDGES) {
        int pos = atomicAdd(&cursor[dst[e]], 1);
        esrc[pos] = src[e];
    }
}

// ---------------- W -> W^T split to bf16 hi/lo ----------------
__global__ void k_cvt_wT(const float* __restrict__ W, __bf16* __restrict__ th,
                         __bf16* __restrict__ tl, int K, int N, int NP) {
    int i = blockIdx.x * 256 + threadIdx.x;
    if (i >= NP * K) return;
    int n = i / K, k = i - n * K;
    float w = (n < N) ? W[(size_t)k * N + n] : 0.f;
    __bf16 h = (__bf16)w;
    th[i] = h;
    tl[i] = (__bf16)(w - (float)h);
}

// ---------------- wide MFMA GEMM: H(Mx256) = A(MxK) @ Bt(256xK)^T ----------------
// Tile 64x256 (all of N), BK=32, 256 threads = 4 waves (1M x 4N), 64x64/wave.
// Grid 782 blocks -> ~3 blocks/CU (was 391x512t at 25% occupancy). Output fp16.
template<bool A_FP32>
__global__ __launch_bounds__(256)
void k_gemm_n256(const float* __restrict__ Af,
                 const __bf16* __restrict__ Ahi, const __bf16* __restrict__ Alo,
                 const __bf16* __restrict__ Bth, const __bf16* __restrict__ Btl,
                 _Float16* __restrict__ H, int M, int K)
{
    __shared__ __bf16 smem[20480];          // 40 KB
    __bf16* sAh = smem;                     // [64][32]
    __bf16* sAl = smem + 2048;
    __bf16* sBh = smem + 4096;              // [256][32]
    __bf16* sBl = smem + 12288;

    const int tid = threadIdx.x;
    const int m0 = blockIdx.y * 64;
    const int lane = tid & 63;
    const int wn = tid >> 6;                // wave id = N-quadrant

    f32x4 acc[4][4];
#pragma unroll
    for (int f = 0; f < 4; ++f)
#pragma unroll
        for (int g = 0; g < 4; ++g)
            acc[f][g] = (f32x4){0.f, 0.f, 0.f, 0.f};

    for (int k0 = 0; k0 < K; k0 += 32) {
        // ---- stage A: 64 rows x 4 slots, one (row,slot) per thread ----
        {
            int row = tid >> 2, slot = tid & 3;
            int gm = m0 + row;
            if (A_FP32) {
                float av[8];
                if (gm < M) {
                    const float* p = Af + (size_t)gm * K + k0 + slot * 8;
                    *(float4*)&av[0] = *(const float4*)(p);
                    *(float4*)&av[4] = *(const float4*)(p + 4);
                } else {
#pragma unroll
                    for (int j = 0; j < 8; ++j) av[j] = 0.f;
                }
                bf16x8 h, l;
#pragma unroll
                for (int j = 0; j < 8; ++j) {
                    __bf16 hh = (__bf16)av[j];
                    h[j] = hh; l[j] = (__bf16)(av[j] - (float)hh);
                }
                *(bf16x8*)&sAh[SWZ(row, slot)] = h;
                *(bf16x8*)&sAl[SWZ(row, slot)] = l;
            } else {
                bf16x8 vh = {}, vl = {};
                if (gm < M) {
                    vh = *(const bf16x8*)(Ahi + (size_t)gm * K + k0 + slot * 8);
                    vl = *(const bf16x8*)(Alo + (size_t)gm * K + k0 + slot * 8);
                }
                *(bf16x8*)&sAh[SWZ(row, slot)] = vh;
                *(bf16x8*)&sAl[SWZ(row, slot)] = vl;
            }
        }
        // ---- stage B: 256 rows x 4 slots, four (row,slot) per thread ----
#pragma unroll
        for (int it = 0; it < 4; ++it) {
            int c = tid + it * 256;
            int row = c >> 2, slot = c & 3;
            size_t off = (size_t)row * K + k0 + slot * 8;
            *(bf16x8*)&sBh[SWZ(row, slot)] = *(const bf16x8*)(Bth + off);
            *(bf16x8*)&sBl[SWZ(row, slot)] = *(const bf16x8*)(Btl + off);
        }
        __syncthreads();

        bf16x8 ah[4], al[4], bh[4], bl[4];
#pragma unroll
        for (int f = 0; f < 4; ++f) {
            int r = f * 16 + (lane & 15);
            ah[f] = *(const bf16x8*)&sAh[SWZ(r, lane >> 4)];
            al[f] = *(const bf16x8*)&sAl[SWZ(r, lane >> 4)];
        }
#pragma unroll
        for (int g = 0; g < 4; ++g) {
            int r = wn * 64 + g * 16 + (lane & 15);
            bh[g] = *(const bf16x8*)&sBh[SWZ(r, lane >> 4)];
            bl[g] = *(const bf16x8*)&sBl[SWZ(r, lane >> 4)];
        }
#pragma unroll
        for (int f = 0; f < 4; ++f)
#pragma unroll
            for (int g = 0; g < 4; ++g) {
                acc[f][g] = __builtin_amdgcn_mfma_f32_16x16x32_bf16(ah[f], bh[g], acc[f][g], 0, 0, 0);
                acc[f][g] = __builtin_amdgcn_mfma_f32_16x16x32_bf16(al[f], bh[g], acc[f][g], 0, 0, 0);
                acc[f][g] = __builtin_amdgcn_mfma_f32_16x16x32_bf16(ah[f], bl[g], acc[f][g], 0, 0, 0);
            }
        __syncthreads();
    }

    // epilogue (fp16 out): col = lane&15 base, row = (lane>>4)*4 + r
#pragma unroll
    for (int f = 0; f < 4; ++f)
#pragma unroll
        for (int g = 0; g < 4; ++g) {
            int col = wn * 64 + g * 16 + (lane & 15);
#pragma unroll
            for (int r = 0; r < 4; ++r) {
                int row = m0 + f * 16 + (lane >> 4) * 4 + r;
                if (row < M) H[(size_t)row * 256 + col] = (_Float16)acc[f][g][r];
            }
        }
}

// ---------------- narrow MFMA GEMM (layer 3): H(MxN) = A(MxK) @ Bt ----------------
// Tile 128x64, BK=32, 4 waves (2M x 2N). Output fp16, row stride N (=60).
__global__ __launch_bounds__(256)
void k_gemm_n64(const __bf16* __restrict__ Ahi, const __bf16* __restrict__ Alo,
                const __bf16* __restrict__ Bth, const __bf16* __restrict__ Btl,
                _Float16* __restrict__ H, int M, int N, int K)
{
    __shared__ __bf16 smem[12288];          // 24 KB
    __bf16* sAh = smem;                     // [128][32]
    __bf16* sAl = smem + 4096;
    __bf16* sBh = smem + 8192;              // [64][32]
    __bf16* sBl = smem + 10240;

    const int tid = threadIdx.x;
    const int m0 = blockIdx.y * 128;
    const int lane = tid & 63, wid = tid >> 6;
    const int wm = wid >> 1, wn = wid & 1;

    f32x4 acc[4][2];
#pragma unroll
    for (int f = 0; f < 4; ++f)
#pragma unroll
        for (int g = 0; g < 2; ++g)
            acc[f][g] = (f32x4){0.f, 0.f, 0.f, 0.f};

    for (int k0 = 0; k0 < K; k0 += 32) {
#pragma unroll
        for (int it = 0; it < 2; ++it) {
            int c = tid + it * 256;
            int row = c >> 2, slot = c & 3;
            int gm = m0 + row;
            bf16x8 vh = {}, vl = {};
            if (gm < M) {
                vh = *(const bf16x8*)(Ahi + (size_t)gm * K + k0 + slot * 8);
                vl = *(const bf16x8*)(Alo + (size_t)gm * K + k0 + slot * 8);
            }
            *(bf16x8*)&sAh[SWZ(row, slot)] = vh;
            *(bf16x8*)&sAl[SWZ(row, slot)] = vl;
        }
        {
            int row = tid >> 2, slot = tid & 3;
            size_t off = (size_t)row * K + k0 + slot * 8;
            *(bf16x8*)&sBh[SWZ(row, slot)] = *(const bf16x8*)(Bth + off);
            *(bf16x8*)&sBl[SWZ(row, slot)] = *(const bf16x8*)(Btl + off);
        }
        __syncthreads();

        bf16x8 ah[4], al[4], bh[2], bl[2];
#pragma unroll
        for (int f = 0; f < 4; ++f) {
            int r = wm * 64 + f * 16 + (lane & 15);
            ah[f] = *(const bf16x8*)&sAh[SWZ(r, lane >> 4)];
            al[f] = *(const bf16x8*)&sAl[SWZ(r, lane >> 4)];
        }
#pragma unroll
        for (int g = 0; g < 2; ++g) {
            int r = wn * 32 + g * 16 + (lane & 15);
            bh[g] = *(const bf16x8*)&sBh[SWZ(r, lane >> 4)];
            bl[g] = *(const bf16x8*)&sBl[SWZ(r, lane >> 4)];
        }
#pragma unroll
        for (int f = 0; f < 4; ++f)
#pragma unroll
            for (int g = 0; g < 2; ++g) {
                acc[f][g] = __builtin_amdgcn_mfma_f32_16x16x32_bf16(ah[f], bh[g], acc[f][g], 0, 0, 0);
                acc[f][g] = __builtin_amdgcn_mfma_f32_16x16x32_bf16(al[f], bh[g], acc[f][g], 0, 0, 0);
                acc[f][g] = __builtin_amdgcn_mfma_f32_16x16x32_bf16(ah[f], bl[g], acc[f][g], 0, 0, 0);
            }
        __syncthreads();
    }

#pragma unroll
    for (int f = 0; f < 4; ++f)
#pragma unroll
        for (int g = 0; g < 2; ++g) {
            int col = wn * 32 + g * 16 + (lane & 15);
            if (col >= N) continue;
#pragma unroll
            for (int r = 0; r < 4; ++r) {
                int row = m0 + wm * 64 + f * 16 + (lane >> 4) * 4 + r;
                if (row < M) H[(size_t)row * N + col] = (_Float16)acc[f][g][r];
            }
        }
}

// ---------------- pull-gather (fp16 in, bf16 hi/lo out), 8x unrolled ----------------
__global__ __launch_bounds__(256)
void k_gather256(const _Float16* __restrict__ H, const int* __restrict__ row_ptr,
                 const int* __restrict__ esrc, const float* __restrict__ dis,
                 const float* __restrict__ bias,
                 __bf16* __restrict__ Ghi, __bf16* __restrict__ Glo)
{
    int wid = threadIdx.x >> 6, lane = threadIdx.x & 63;
    int v = blockIdx.x * 4 + wid;
    if (v >= N_NODES) return;
    const f16x4* H4 = (const f16x4*)H;
    float dv = dis[v], d2 = dv * dv;
    float4 b = ((const float4*)bias)[lane];
    f16x4 hv = H4[(size_t)v * 64 + lane];
    float a0 = fmaf((float)hv[0], d2, b.x);
    float a1 = fmaf((float)hv[1], d2, b.y);
    float a2 = fmaf((float)hv[2], d2, b.z);
    float a3 = fmaf((float)hv[3], d2, b.w);

    int e = row_ptr[v], e1 = row_ptr[v + 1];
    for (; e + 7 < e1; e += 8) {
        int s[8];
        float n[8];
        f16x4 h[8];
#pragma unroll
        for (int j = 0; j < 8; ++j) s[j] = esrc[e + j];
#pragma unroll
        for (int j = 0; j < 8; ++j) n[j] = dis[s[j]] * dv;
#pragma unroll
        for (int j = 0; j < 8; ++j) h[j] = H4[(size_t)s[j] * 64 + lane];
#pragma unroll
        for (int j = 0; j < 8; ++j) {
            a0 = fmaf((float)h[j][0], n[j], a0);
            a1 = fmaf((float)h[j][1], n[j], a1);
            a2 = fmaf((float)h[j][2], n[j], a2);
            a3 = fmaf((float)h[j][3], n[j], a3);
        }
    }
    for (; e < e1; ++e) {
        int s = esrc[e];
        float nn = dis[s] * dv;
        f16x4 h = H4[(size_t)s * 64 + lane];
        a0 = fmaf((float)h[0], nn, a0); a1 = fmaf((float)h[1], nn, a1);
        a2 = fmaf((float)h[2], nn, a2); a3 = fmaf((float)h[3], nn, a3);
    }
    a0 = fmaxf(a0, 0.f); a1 = fmaxf(a1, 0.f);
    a2 = fmaxf(a2, 0.f); a3 = fmaxf(a3, 0.f);

    bf16x4 h, l;
    h[0] = (__bf16)a0; l[0] = (__bf16)(a0 - (float)h[0]);
    h[1] = (__bf16)a1; l[1] = (__bf16)(a1 - (float)h[1]);
    h[2] = (__bf16)a2; l[2] = (__bf16)(a2 - (float)h[2]);
    h[3] = (__bf16)a3; l[3] = (__bf16)(a3 - (float)h[3]);
    size_t o = (size_t)v * 256 + lane * 4;
    *(bf16x4*)&Ghi[o] = h;
    *(bf16x4*)&Glo[o] = l;
}

__global__ __launch_bounds__(256)
void k_gather60(const _Float16* __restrict__ H3, const int* __restrict__ row_ptr,
                const int* __restrict__ esrc, const float* __restrict__ dis,
                const float* __restrict__ b3, float* __restrict__ out)
{
    int wid = threadIdx.x >> 6, lane = threadIdx.x & 63;
    int v = blockIdx.x * 4 + wid;
    if (v >= N_NODES || lane >= 30) return;
    const f16x2* H2 = (const f16x2*)H3;
    float dv = dis[v], d2 = dv * dv;
    f16x2 hv = H2[(size_t)v * 30 + lane];
    float a0 = fmaf((float)hv[0], d2, b3[lane * 2]);
    float a1 = fmaf((float)hv[1], d2, b3[lane * 2 + 1]);
    int e = row_ptr[v], e1 = row_ptr[v + 1];
    for (; e + 1 < e1; e += 2) {
        int s0 = esrc[e], s1 = esrc[e + 1];
        float n0 = dis[s0] * dv, n1 = dis[s1] * dv;
        f16x2 h0 = H2[(size_t)s0 * 30 + lane];
        f16x2 h1 = H2[(size_t)s1 * 30 + lane];
        a0 = fmaf((float)h0[0], n0, a0); a1 = fmaf((float)h0[1], n0, a1);
        a0 = fmaf((float)h1[0], n1, a0); a1 = fmaf((float)h1[1], n1, a1);
    }
    if (e < e1) {
        int s = esrc[e];
        float n = dis[s] * dv;
        f16x2 h = H2[(size_t)s * 30 + lane];
        a0 = fmaf((float)h[0], n, a0); a1 = fmaf((float)h[1], n, a1);
    }
    out[(size_t)v * 60 + lane * 2]     = a0;
    out[(size_t)v * 60 + lane * 2 + 1] = a1;
}

// ---------------- launch ----------------
extern "C" void kernel_launch(void* const* d_in, const int* in_sizes, int n_in,
                              void* d_out, int out_size, void* d_ws, size_t ws_size,
                              hipStream_t stream)
{
    const float* x  = (const float*)d_in[0];
    const int*   ei = (const int*)d_in[1];
    const float* W1 = (const float*)d_in[3];
    const float* b1 = (const float*)d_in[4];
    const float* W2 = (const float*)d_in[5];
    const float* b2 = (const float*)d_in[6];
    const float* W3 = (const float*)d_in[7];
    const float* b3 = (const float*)d_in[8];
    float* out = (float*)d_out;

    const int* src = ei;
    const int* dst = ei + N_EDGES;

    char* ws = (char*)d_ws;
    int*      cnt      = (int*)(ws + 0);
    float*    dis      = (float*)(ws + 200704);
    int*      scanned  = (int*)(ws + 401408);
    int*      blocksum = (int*)(ws + 602112);
    int*      blockoff = (int*)(ws + 603136);
    int*      row_ptr  = (int*)(ws + 604160);
    int*      cursor   = (int*)(ws + 805376);
    int*      esrc     = (int*)(ws + 1006080);
    __bf16*   w1h      = (__bf16*)(ws + 4206592);
    __bf16*   w1l      = (__bf16*)(ws + 4468736);
    __bf16*   w2h      = (__bf16*)(ws + 4730880);
    __bf16*   w2l      = (__bf16*)(ws + 4861952);
    __bf16*   w3h      = (__bf16*)(ws + 4993024);
    __bf16*   w3l      = (__bf16*)(ws + 5025792);
    _Float16* H        = (_Float16*)(ws + 5058560);    // 25.6 MB
    __bf16*   Ghi      = (__bf16*)(ws + 30658560);     // 25.6 MB
    __bf16*   Glo      = (__bf16*)(ws + 56258560);     // 25.6 MB
    _Float16* H3       = (_Float16*)(ws + 81858560);   // 6.0 MB

    // ---- CSR build + normalization ----
    k_cnt_zero<<<SCAN_BLOCKS, 256, 0, stream>>>(cnt);
    k_deg_count<<<(N_EDGES + 255) / 256, 256, 0, stream>>>(dst, cnt);
    k_dis<<<SCAN_BLOCKS, 256, 0, stream>>>(cnt, dis);
    k_scan1<<<SCAN_BLOCKS, 256, 0, stream>>>(cnt, scanned, blocksum);
    k_scan2<<<1, 256, 0, stream>>>(blocksum, blockoff);
    k_scan3<<<SCAN_BLOCKS, 256, 0, stream>>>(scanned, blockoff, row_ptr, cursor);
    k_fill<<<(N_EDGES + 255) / 256, 256, 0, stream>>>(src, dst, cursor, esrc);

    // ---- weight transpose + split ----
    k_cvt_wT<<<(256 * 512 + 255) / 256, 256, 0, stream>>>(W1, w1h, w1l, 512, 256, 256);
    k_cvt_wT<<<(256 * 256 + 255) / 256, 256, 0, stream>>>(W2, w2h, w2l, 256, 256, 256);
    k_cvt_wT<<<(64 * 256 + 255) / 256, 256, 0, stream>>>(W3, w3h, w3l, 256, 60, 64);

    const int MB64  = (N_NODES + 63) / 64;     // 782
    const int MB128 = (N_NODES + 127) / 128;   // 391
    const int GB    = (N_NODES + 3) / 4;       // 12500

    // layer 1
    k_gemm_n256<true><<<dim3(1, MB64), 256, 0, stream>>>(x, nullptr, nullptr, w1h, w1l,
                                                         H, N_NODES, F_IN);
    k_gather256<<<GB, 256, 0, stream>>>(H, row_ptr, esrc, dis, b1, Ghi, Glo);
    // layer 2
    k_gemm_n256<false><<<dim3(1, MB64), 256, 0, stream>>>(nullptr, Ghi, Glo, w2h, w2l,
                                                          H, N_NODES, F_HID);
    k_gather256<<<GB, 256, 0, stream>>>(H, row_ptr, esrc, dis, b2, Ghi, Glo);
    // layer 3 (pool identity, dropout identity)
    k_gemm_n64<<<dim3(1, MB128), 256, 0, stream>>>(Ghi, Glo, w3h, w3l, H3, N_NODES, F_OUT, F_HID);
    k_gather60<<<GB, 256, 0, stream>>>(H3, row_ptr, esrc, dis, b3, out);
}

// Round 12
// 524.091 us; speedup vs baseline: 1.0058x; 1.0058x over previous
//
#include <hip/hip_runtime.h>

#define N_NODES 50000
#define N_EDGES 800000
#define F_IN    512
#define F_HID   256
#define F_OUT   60
#define SCAN_BLOCKS ((N_NODES + 255) / 256)   // 196

typedef __bf16    bf16x8 __attribute__((ext_vector_type(8)));
typedef __bf16    bf16x4 __attribute__((ext_vector_type(4)));
typedef float     f32x4  __attribute__((ext_vector_type(4)));
typedef _Float16  f16x4  __attribute__((ext_vector_type(4)));
typedef _Float16  f16x2  __attribute__((ext_vector_type(2)));

// Swizzled LDS index (bf16 units) for [row][32] tiles (64 B rows).
// slot = 16B group (8 bf16). XOR with (row>>1)&3: conflict-free ds_read_b128 /
// ds_write_b128 on both staging and fragment-read sides (bijective per row).
__device__ __forceinline__ int SWZ(int row, int slot) {
    return row * 32 + (((slot) ^ ((row >> 1) & 3)) << 3);
}

// ---------------- degree / CSR build ----------------
__global__ void k_cnt_zero(int* __restrict__ cnt) {
    int i = blockIdx.x * blockDim.x + threadIdx.x;
    if (i < N_NODES) cnt[i] = 0;
}
__global__ void k_deg_count(const int* __restrict__ dst, int* __restrict__ cnt) {
    int i = blockIdx.x * blockDim.x + threadIdx.x;
    if (i < N_EDGES) atomicAdd(&cnt[dst[i]], 1);
}
__global__ void k_dis(const int* __restrict__ cnt, float* __restrict__ dis) {
    int i = blockIdx.x * blockDim.x + threadIdx.x;
    if (i < N_NODES) dis[i] = rsqrtf((float)(cnt[i] + 1));   // +1 self loop
}
__global__ void k_scan1(const int* __restrict__ cnt, int* __restrict__ scanned,
                        int* __restrict__ blocksum) {
    __shared__ int tmp[256];
    int i = blockIdx.x * 256 + threadIdx.x;
    int v = (i < N_NODES) ? cnt[i] : 0;
    tmp[threadIdx.x] = v;
    __syncthreads();
    for (int off = 1; off < 256; off <<= 1) {
        int t = (threadIdx.x >= off) ? tmp[threadIdx.x - off] : 0;
        __syncthreads();
        tmp[threadIdx.x] += t;
        __syncthreads();
    }
    if (i < N_NODES) scanned[i] = tmp[threadIdx.x] - v;
    if (threadIdx.x == 255) blocksum[blockIdx.x] = tmp[255];
}
__global__ void k_scan2(const int* __restrict__ blocksum, int* __restrict__ blockoff) {
    __shared__ int tmp[256];
    int v = (threadIdx.x < SCAN_BLOCKS) ? blocksum[threadIdx.x] : 0;
    tmp[threadIdx.x] = v;
    __syncthreads();
    for (int off = 1; off < 256; off <<= 1) {
        int t = (threadIdx.x >= off) ? tmp[threadIdx.x - off] : 0;
        __syncthreads();
        tmp[threadIdx.x] += t;
        __syncthreads();
    }
    if (threadIdx.x < SCAN_BLOCKS) blockoff[threadIdx.x] = tmp[threadIdx.x] - v;
}
__global__ void k_scan3(const int* __restrict__ scanned, const int* __restrict__ blockoff,
                        int* __restrict__ row_ptr, int* __restrict__ cursor) {
    int i = blockIdx.x * 256 + threadIdx.x;
    if (i < N_NODES) {
        int rp = scanned[i] + blockoff[blockIdx.x];
        row_ptr[i] = rp;
        cursor[i] = rp;
    }
    if (i == 0) row_ptr[N_NODES] = N_EDGES;
}
__global__ void k_fill(const int* __restrict__ src, const int* __restrict__ dst,
                       int* __restrict__ cursor, int* __restrict__ esrc) {
    int e = blockIdx.x * blockDim.x + threadIdx.x;
    if (e < N_EDGES) {
        int pos = atomicAdd(&cursor[dst[e]], 1);
        esrc[pos] = src[e];
    }
}

// ---------------- W -> W^T split to bf16 hi/lo ----------------
__global__ void k_cvt_wT(const float* __restrict__ W, __bf16* __restrict__ th,
                         __bf16* __restrict__ tl, int K, int N, int NP) {
    int i = blockIdx.x * 256 + threadIdx.x;
    if (i >= NP * K) return;
    int n = i / K, k = i - n * K;
    float w = (n < N) ? W[(size_t)k * N + n] : 0.f;
    __bf16 h = (__bf16)w;
    th[i] = h;
    tl[i] = (__bf16)(w - (float)h);
}

// ---------------- wide MFMA GEMM: H(Mx256) = A(MxK) @ Bt(256xK)^T ----------------
// Tile 128x256 (all of N), BK=32, 512 threads = 8 waves (2M x 4N), 64x64/wave.
// Software-pipelined: tile k+1 is loaded to REGISTERS right after the
// fragment ds_reads of tile k, so HBM latency hides under the 48-MFMA cluster;
// the reg->LDS write happens after the next barrier (T14 issue-early).
template<bool A_FP32>
__global__ __launch_bounds__(512)
void k_gemm_n256(const float* __restrict__ Af,
                 const __bf16* __restrict__ Ahi, const __bf16* __restrict__ Alo,
                 const __bf16* __restrict__ Bth, const __bf16* __restrict__ Btl,
                 _Float16* __restrict__ H, int M, int K)
{
    __shared__ __bf16 smem[24576];          // 48 KB
    __bf16* sAh = smem;                     // [128][32]
    __bf16* sAl = smem + 4096;
    __bf16* sBh = smem + 8192;              // [256][32]
    __bf16* sBl = smem + 16384;

    const int tid = threadIdx.x;
    const int m0 = blockIdx.y * 128;
    const int lane = tid & 63, wid = tid >> 6;
    const int wm = wid >> 2, wn = wid & 3;

    const int arow = tid >> 2, aslot = tid & 3;        // A: 128 rows x 4 slots
    const int brow = tid >> 1, bslot0 = (tid & 1) * 2; // B: 256 rows, 2 slots/thread
    const int gm = m0 + arow;

    // prefetch registers
    float  avf[8];
    bf16x8 avh = {}, avl = {};
    bf16x8 bvh0, bvh1, bvl0, bvl1;

    auto load_tile = [&](int k0) {
        if (A_FP32) {
            if (gm < M) {
                const float* p = Af + (size_t)gm * K + k0 + aslot * 8;
                *(float4*)&avf[0] = *(const float4*)(p);
                *(float4*)&avf[4] = *(const float4*)(p + 4);
            } else {
#pragma unroll
                for (int j = 0; j < 8; ++j) avf[j] = 0.f;
            }
        } else {
            if (gm < M) {
                avh = *(const bf16x8*)(Ahi + (size_t)gm * K + k0 + aslot * 8);
                avl = *(const bf16x8*)(Alo + (size_t)gm * K + k0 + aslot * 8);
            } else {
                avh = (bf16x8){}; avl = (bf16x8){};
            }
        }
        size_t off = (size_t)brow * K + k0 + bslot0 * 8;
        bvh0 = *(const bf16x8*)(Bth + off);
        bvh1 = *(const bf16x8*)(Bth + off + 8);
        bvl0 = *(const bf16x8*)(Btl + off);
        bvl1 = *(const bf16x8*)(Btl + off + 8);
    };

    f32x4 acc[4][4];
#pragma unroll
    for (int f = 0; f < 4; ++f)
#pragma unroll
        for (int g = 0; g < 4; ++g)
            acc[f][g] = (f32x4){0.f, 0.f, 0.f, 0.f};

    load_tile(0);   // prologue

    for (int k0 = 0; k0 < K; k0 += 32) {
        if (k0) __syncthreads();            // prior iter's ds_reads complete
        // ---- write staged registers to LDS ----
        if (A_FP32) {
            bf16x8 h, l;
#pragma unroll
            for (int j = 0; j < 8; ++j) {
                __bf16 hh = (__bf16)avf[j];
                h[j] = hh; l[j] = (__bf16)(avf[j] - (float)hh);
            }
            *(bf16x8*)&sAh[SWZ(arow, aslot)] = h;
            *(bf16x8*)&sAl[SWZ(arow, aslot)] = l;
        } else {
            *(bf16x8*)&sAh[SWZ(arow, aslot)] = avh;
            *(bf16x8*)&sAl[SWZ(arow, aslot)] = avl;
        }
        *(bf16x8*)&sBh[SWZ(brow, bslot0)]     = bvh0;
        *(bf16x8*)&sBh[SWZ(brow, bslot0 + 1)] = bvh1;
        *(bf16x8*)&sBl[SWZ(brow, bslot0)]     = bvl0;
        *(bf16x8*)&sBl[SWZ(brow, bslot0 + 1)] = bvl1;
        __syncthreads();

        // ---- fragment ds_reads ----
        bf16x8 ah[4], al[4], bh[4], bl[4];
#pragma unroll
        for (int f = 0; f < 4; ++f) {
            int r = wm * 64 + f * 16 + (lane & 15);
            ah[f] = *(const bf16x8*)&sAh[SWZ(r, lane >> 4)];
            al[f] = *(const bf16x8*)&sAl[SWZ(r, lane >> 4)];
        }
#pragma unroll
        for (int g = 0; g < 4; ++g) {
            int r = wn * 64 + g * 16 + (lane & 15);
            bh[g] = *(const bf16x8*)&sBh[SWZ(r, lane >> 4)];
            bl[g] = *(const bf16x8*)&sBl[SWZ(r, lane >> 4)];
        }

        // ---- issue next tile's global loads (latency hides under MFMA) ----
        if (k0 + 32 < K) load_tile(k0 + 32);

        // ---- MFMA cluster ----
#pragma unroll
        for (int f = 0; f < 4; ++f)
#pragma unroll
            for (int g = 0; g < 4; ++g) {
                acc[f][g] = __builtin_amdgcn_mfma_f32_16x16x32_bf16(ah[f], bh[g], acc[f][g], 0, 0, 0);
                acc[f][g] = __builtin_amdgcn_mfma_f32_16x16x32_bf16(al[f], bh[g], acc[f][g], 0, 0, 0);
                acc[f][g] = __builtin_amdgcn_mfma_f32_16x16x32_bf16(ah[f], bl[g], acc[f][g], 0, 0, 0);
            }
    }

    // epilogue (fp16 out): col = lane&15 base, row = (lane>>4)*4 + r
#pragma unroll
    for (int f = 0; f < 4; ++f)
#pragma unroll
        for (int g = 0; g < 4; ++g) {
            int col = wn * 64 + g * 16 + (lane & 15);
#pragma unroll
            for (int r = 0; r < 4; ++r) {
                int row = m0 + wm * 64 + f * 16 + (lane >> 4) * 4 + r;
                if (row < M) H[(size_t)row * 256 + col] = (_Float16)acc[f][g][r];
            }
        }
}

// ---------------- narrow MFMA GEMM (layer 3): H(MxN) = A(MxK) @ Bt ----------------
// Tile 128x64, BK=32, 4 waves (2M x 2N). Output fp16, row stride N (=60).
__global__ __launch_bounds__(256)
void k_gemm_n64(const __bf16* __restrict__ Ahi, const __bf16* __restrict__ Alo,
                const __bf16* __restrict__ Bth, const __bf16* __restrict__ Btl,
                _Float16* __restrict__ H, int M, int N, int K)
{
    __shared__ __bf16 smem[12288];          // 24 KB
    __bf16* sAh = smem;                     // [128][32]
    __bf16* sAl = smem + 4096;
    __bf16* sBh = smem + 8192;              // [64][32]
    __bf16* sBl = smem + 10240;

    const int tid = threadIdx.x;
    const int m0 = blockIdx.y * 128;
    const int lane = tid & 63, wid = tid >> 6;
    const int wm = wid >> 1, wn = wid & 1;

    f32x4 acc[4][2];
#pragma unroll
    for (int f = 0; f < 4; ++f)
#pragma unroll
        for (int g = 0; g < 2; ++g)
            acc[f][g] = (f32x4){0.f, 0.f, 0.f, 0.f};

    for (int k0 = 0; k0 < K; k0 += 32) {
#pragma unroll
        for (int it = 0; it < 2; ++it) {
            int c = tid + it * 256;
            int row = c >> 2, slot = c & 3;
            int gm = m0 + row;
            bf16x8 vh = {}, vl = {};
            if (gm < M) {
                vh = *(const bf16x8*)(Ahi + (size_t)gm * K + k0 + slot * 8);
                vl = *(const bf16x8*)(Alo + (size_t)gm * K + k0 + slot * 8);
            }
            *(bf16x8*)&sAh[SWZ(row, slot)] = vh;
            *(bf16x8*)&sAl[SWZ(row, slot)] = vl;
        }
        {
            int row = tid >> 2, slot = tid & 3;
            size_t off = (size_t)row * K + k0 + slot * 8;
            *(bf16x8*)&sBh[SWZ(row, slot)] = *(const bf16x8*)(Bth + off);
            *(bf16x8*)&sBl[SWZ(row, slot)] = *(const bf16x8*)(Btl + off);
        }
        __syncthreads();

        bf16x8 ah[4], al[4], bh[2], bl[2];
#pragma unroll
        for (int f = 0; f < 4; ++f) {
            int r = wm * 64 + f * 16 + (lane & 15);
            ah[f] = *(const bf16x8*)&sAh[SWZ(r, lane >> 4)];
            al[f] = *(const bf16x8*)&sAl[SWZ(r, lane >> 4)];
        }
#pragma unroll
        for (int g = 0; g < 2; ++g) {
            int r = wn * 32 + g * 16 + (lane & 15);
            bh[g] = *(const bf16x8*)&sBh[SWZ(r, lane >> 4)];
            bl[g] = *(const bf16x8*)&sBl[SWZ(r, lane >> 4)];
        }
#pragma unroll
        for (int f = 0; f < 4; ++f)
#pragma unroll
            for (int g = 0; g < 2; ++g) {
                acc[f][g] = __builtin_amdgcn_mfma_f32_16x16x32_bf16(ah[f], bh[g], acc[f][g], 0, 0, 0);
                acc[f][g] = __builtin_amdgcn_mfma_f32_16x16x32_bf16(al[f], bh[g], acc[f][g], 0, 0, 0);
                acc[f][g] = __builtin_amdgcn_mfma_f32_16x16x32_bf16(ah[f], bl[g], acc[f][g], 0, 0, 0);
            }
        __syncthreads();
    }

#pragma unroll
    for (int f = 0; f < 4; ++f)
#pragma unroll
        for (int g = 0; g < 2; ++g) {
            int col = wn * 32 + g * 16 + (lane & 15);
            if (col >= N) continue;
#pragma unroll
            for (int r = 0; r < 4; ++r) {
                int row = m0 + wm * 64 + f * 16 + (lane >> 4) * 4 + r;
                if (row < M) H[(size_t)row * N + col] = (_Float16)acc[f][g][r];
            }
        }
}

// ---------------- pull-gather (fp16 in, bf16 hi/lo out), 8x unrolled ----------------
__global__ __launch_bounds__(256)
void k_gather256(const _Float16* __restrict__ H, const int* __restrict__ row_ptr,
                 const int* __restrict__ esrc, const float* __restrict__ dis,
                 const float* __restrict__ bias,
                 __bf16* __restrict__ Ghi, __bf16* __restrict__ Glo)
{
    int wid = threadIdx.x >> 6, lane = threadIdx.x & 63;
    int v = blockIdx.x * 4 + wid;
    if (v >= N_NODES) return;
    const f16x4* H4 = (const f16x4*)H;
    float dv = dis[v], d2 = dv * dv;
    float4 b = ((const float4*)bias)[lane];
    f16x4 hv = H4[(size_t)v * 64 + lane];
    float a0 = fmaf((float)hv[0], d2, b.x);
    float a1 = fmaf((float)hv[1], d2, b.y);
    float a2 = fmaf((float)hv[2], d2, b.z);
    float a3 = fmaf((float)hv[3], d2, b.w);

    int e = row_ptr[v], e1 = row_ptr[v + 1];
    for (; e + 7 < e1; e += 8) {
        int s[8];
        float n[8];
        f16x4 h[8];
#pragma unroll
        for (int j = 0; j < 8; ++j) s[j] = esrc[e + j];
#pragma unroll
        for (int j = 0; j < 8; ++j) n[j] = dis[s[j]] * dv;
#pragma unroll
        for (int j = 0; j < 8; ++j) h[j] = H4[(size_t)s[j] * 64 + lane];
#pragma unroll
        for (int j = 0; j < 8; ++j) {
            a0 = fmaf((float)h[j][0], n[j], a0);
            a1 = fmaf((float)h[j][1], n[j], a1);
            a2 = fmaf((float)h[j][2], n[j], a2);
            a3 = fmaf((float)h[j][3], n[j], a3);
        }
    }
    for (; e < e1; ++e) {
        int s = esrc[e];
        float nn = dis[s] * dv;
        f16x4 h = H4[(size_t)s * 64 + lane];
        a0 = fmaf((float)h[0], nn, a0); a1 = fmaf((float)h[1], nn, a1);
        a2 = fmaf((float)h[2], nn, a2); a3 = fmaf((float)h[3], nn, a3);
    }
    a0 = fmaxf(a0, 0.f); a1 = fmaxf(a1, 0.f);
    a2 = fmaxf(a2, 0.f); a3 = fmaxf(a3, 0.f);

    bf16x4 h, l;
    h[0] = (__bf16)a0; l[0] = (__bf16)(a0 - (float)h[0]);
    h[1] = (__bf16)a1; l[1] = (__bf16)(a1 - (float)h[1]);
    h[2] = (__bf16)a2; l[2] = (__bf16)(a2 - (float)h[2]);
    h[3] = (__bf16)a3; l[3] = (__bf16)(a3 - (float)h[3]);
    size_t o = (size_t)v * 256 + lane * 4;
    *(bf16x4*)&Ghi[o] = h;
    *(bf16x4*)&Glo[o] = l;
}

__global__ __launch_bounds__(256)
void k_gather60(const _Float16* __restrict__ H3, const int* __restrict__ row_ptr,
                const int* __restrict__ esrc, const float* __restrict__ dis,
                const float* __restrict__ b3, float* __restrict__ out)
{
    int wid = threadIdx.x >> 6, lane = threadIdx.x & 63;
    int v = blockIdx.x * 4 + wid;
    if (v >= N_NODES || lane >= 30) return;
    const f16x2* H2 = (const f16x2*)H3;
    float dv = dis[v], d2 = dv * dv;
    f16x2 hv = H2[(size_t)v * 30 + lane];
    float a0 = fmaf((float)hv[0], d2, b3[lane * 2]);
    float a1 = fmaf((float)hv[1], d2, b3[lane * 2 + 1]);
    int e = row_ptr[v], e1 = row_ptr[v + 1];
    for (; e + 1 < e1; e += 2) {
        int s0 = esrc[e], s1 = esrc[e + 1];
        float n0 = dis[s0] * dv, n1 = dis[s1] * dv;
        f16x2 h0 = H2[(size_t)s0 * 30 + lane];
        f16x2 h1 = H2[(size_t)s1 * 30 + lane];
        a0 = fmaf((float)h0[0], n0, a0); a1 = fmaf((float)h0[1], n0, a1);
        a0 = fmaf((float)h1[0], n1, a0); a1 = fmaf((float)h1[1], n1, a1);
    }
    if (e < e1) {
        int s = esrc[e];
        float n = dis[s] * dv;
        f16x2 h = H2[(size_t)s * 30 + lane];
        a0 = fmaf((float)h[0], n, a0); a1 = fmaf((float)h[1], n, a1);
    }
    out[(size_t)v * 60 + lane * 2]     = a0;
    out[(size_t)v * 60 + lane * 2 + 1] = a1;
}

// ---------------- launch ----------------
extern "C" void kernel_launch(void* const* d_in, const int* in_sizes, int n_in,
                              void* d_out, int out_size, void* d_ws, size_t ws_size,
                              hipStream_t stream)
{
    const float* x  = (const float*)d_in[0];
    const int*   ei = (const int*)d_in[1];
    const float* W1 = (const float*)d_in[3];
    const float* b1 = (const float*)d_in[4];
    const float* W2 = (const float*)d_in[5];
    const float* b2 = (const float*)d_in[6];
    const float* W3 = (const float*)d_in[7];
    const float* b3 = (const float*)d_in[8];
    float* out = (float*)d_out;

    const int* src = ei;
    const int* dst = ei + N_EDGES;

    char* ws = (char*)d_ws;
    int*      cnt      = (int*)(ws + 0);
    float*    dis      = (float*)(ws + 200704);
    int*      scanned  = (int*)(ws + 401408);
    int*      blocksum = (int*)(ws + 602112);
    int*      blockoff = (int*)(ws + 603136);
    int*      row_ptr  = (int*)(ws + 604160);
    int*      cursor   = (int*)(ws + 805376);
    int*      esrc     = (int*)(ws + 1006080);
    __bf16*   w1h      = (__bf16*)(ws + 4206592);
    __bf16*   w1l      = (__bf16*)(ws + 4468736);
    __bf16*   w2h      = (__bf16*)(ws + 4730880);
    __bf16*   w2l      = (__bf16*)(ws + 4861952);
    __bf16*   w3h      = (__bf16*)(ws + 4993024);
    __bf16*   w3l      = (__bf16*)(ws + 5025792);
    _Float16* H        = (_Float16*)(ws + 5058560);    // 25.6 MB
    __bf16*   Ghi      = (__bf16*)(ws + 30658560);     // 25.6 MB
    __bf16*   Glo      = (__bf16*)(ws + 56258560);     // 25.6 MB
    _Float16* H3       = (_Float16*)(ws + 81858560);   // 6.0 MB

    // ---- CSR build + normalization ----
    k_cnt_zero<<<SCAN_BLOCKS, 256, 0, stream>>>(cnt);
    k_deg_count<<<(N_EDGES + 255) / 256, 256, 0, stream>>>(dst, cnt);
    k_dis<<<SCAN_BLOCKS, 256, 0, stream>>>(cnt, dis);
    k_scan1<<<SCAN_BLOCKS, 256, 0, stream>>>(cnt, scanned, blocksum);
    k_scan2<<<1, 256, 0, stream>>>(blocksum, blockoff);
    k_scan3<<<SCAN_BLOCKS, 256, 0, stream>>>(scanned, blockoff, row_ptr, cursor);
    k_fill<<<(N_EDGES + 255) / 256, 256, 0, stream>>>(src, dst, cursor, esrc);

    // ---- weight transpose + split ----
    k_cvt_wT<<<(256 * 512 + 255) / 256, 256, 0, stream>>>(W1, w1h, w1l, 512, 256, 256);
    k_cvt_wT<<<(256 * 256 + 255) / 256, 256, 0, stream>>>(W2, w2h, w2l, 256, 256, 256);
    k_cvt_wT<<<(64 * 256 + 255) / 256, 256, 0, stream>>>(W3, w3h, w3l, 256, 60, 64);

    const int MB128 = (N_NODES + 127) / 128;   // 391
    const int GB    = (N_NODES + 3) / 4;       // 12500

    // layer 1
    k_gemm_n256<true><<<dim3(1, MB128), 512, 0, stream>>>(x, nullptr, nullptr, w1h, w1l,
                                                          H, N_NODES, F_IN);
    k_gather256<<<GB, 256, 0, stream>>>(H, row_ptr, esrc, dis, b1, Ghi, Glo);
    // layer 2
    k_gemm_n256<false><<<dim3(1, MB128), 512, 0, stream>>>(nullptr, Ghi, Glo, w2h, w2l,
                                                           H, N_NODES, F_HID);
    k_gather256<<<GB, 256, 0, stream>>>(H, row_ptr, esrc, dis, b2, Ghi, Glo);
    // layer 3 (pool identity, dropout identity)
    k_gemm_n64<<<dim3(1, MB128), 256, 0, stream>>>(Ghi, Glo, w3h, w3l, H3, N_NODES, F_OUT, F_HID);
    k_gather60<<<GB, 256, 0, stream>>>(H3, row_ptr, esrc, dis, b3, out);
}